// Round 6
// baseline (220.015 us; speedup 1.0000x reference)
//
#include <hip/hip_runtime.h>
#include <hip/hip_cooperative_groups.h>
#include <math.h>

namespace cg = cooperative_groups;

#define L    4096
#define DI   128
#define NS   16
#define KK   6
#define CM   64     // d_model
#define NC   256    // chunks per direction
#define CH   16     // steps per chunk
#define NU   (KK*NC)   // 1536 work units
#define SHSZ 2688

__device__ __forceinline__ float softplus_f(float x){
    return x > 20.f ? x : __logf(1.f + __expf(x));
}
__device__ __forceinline__ float silu_f(float x){
    return x / (1.f + __expf(-x));
}

// anti-diagonal rank of pixel p (closed form)
__device__ __forceinline__ int rankp(int p){
    int h = p >> 6, w = p & 63, s = h + w;
    int imin = s > 63 ? s - 63 : 0;
    int off = (s < 64) ? (s*(s+1))/2 : 4096 - ((127-s)*(128-s))/2;
    return off + (h - imin);
}
// inverse: pixel with anti-diagonal rank l
__device__ __forceinline__ int diag_pix(int l){
    if(l < 2080){
        int s = (int)((sqrtf(8.f*(float)l + 1.f) - 1.f)*0.5f);
        if((s+1)*(s+2)/2 <= l) s++;
        else if(s*(s+1)/2 > l) s--;
        int t = l - s*(s+1)/2;
        return t*64 + (s - t);
    } else {
        int r = 4096 - l;   // 1..2016
        int q = (int)((sqrtf(8.f*(float)r + 1.f) - 1.f)*0.5f);
        if(q*(q+1)/2 < r) q++;
        else if((q-1)*q/2 >= r) q--;
        int s = 127 - q;
        int off = 4096 - q*(q+1)/2;
        int t = l - off;
        int h = (s - 63) + t;
        return h*64 + (s - h);
    }
}
__device__ __forceinline__ int perm_in(int k, int l){
    switch(k){
        case 0: return l;
        case 1: return ((l&63)<<6) | (l>>6);
        case 2: return (L-1) - l;
        case 3: { int m = (L-1)-l; return ((m&63)<<6) | (m>>6); }
        case 4: return diag_pix(l);
        default: return diag_pix(l) ^ 63;
    }
}

// ================= front: in_proj + depthwise conv fused =================
__global__ __launch_bounds__(256) void k_front(const float* __restrict__ x,
                                               const float* __restrict__ W_in,
                                               const float* __restrict__ cw,
                                               const float* __restrict__ cb,
                                               float* __restrict__ xc_t,
                                               float* __restrict__ sz){
    int ty = blockIdx.x >> 4, tx = blockIdx.x & 15;
    int h0 = ty*4, w0 = tx*4;
    int t = threadIdx.x;
    __shared__ float xr[36*CM];
    __shared__ float xxs[36*DI];

    for(int lin = t; lin < 36*16; lin += 256){
        int px = lin >> 4, c4 = lin & 15;
        int hh = h0 - 1 + px/6, ww = w0 - 1 + px%6;
        float4 v = make_float4(0.f,0.f,0.f,0.f);
        if(hh >= 0 && hh < 64 && ww >= 0 && ww < 64)
            v = ((const float4*)(x + (size_t)(hh*64+ww)*CM))[c4];
        *((float4*)(xr + px*CM + c4*4)) = v;
    }
    __syncthreads();

    int o = t;
    float4 w[16];
    const float4* wrow = (const float4*)(W_in + (size_t)o*CM);
    #pragma unroll
    for(int q=0;q<16;q++) w[q] = wrow[q];
    for(int px=0; px<36; px++){
        const float4* xv4 = (const float4*)(xr + px*CM);
        float acc = 0.f;
        #pragma unroll
        for(int q=0;q<16;q++){
            float4 xv = xv4[q];
            acc += w[q].x*xv.x + w[q].y*xv.y + w[q].z*xv.z + w[q].w*xv.w;
        }
        if(o < DI) xxs[px*DI + o] = acc;
        else {
            int hr = px/6, wc = px%6;
            if(hr >= 1 && hr <= 4 && wc >= 1 && wc <= 4){
                int pg = (h0 + hr - 1)*64 + (w0 + wc - 1);
                sz[(size_t)pg*DI + (o-DI)] = silu_f(acc);
            }
        }
    }
    __syncthreads();

    int d = t & 127, ph = t >> 7;
    float cwr[9];
    #pragma unroll
    for(int j=0;j<9;j++) cwr[j] = cw[d*9+j];
    float cbd = cb[d];
    #pragma unroll
    for(int i=0;i<8;i++){
        int idx = ph*8 + i;
        int r = idx >> 2, c = idx & 3;
        float acc = cbd;
        #pragma unroll
        for(int dh=0; dh<3; dh++)
            #pragma unroll
            for(int dw=0; dw<3; dw++)
                acc += cwr[dh*3+dw] * xxs[((r+dh)*6 + (c+dw))*DI + d];
        int pg = (h0+r)*64 + (w0+c);
        xc_t[(size_t)pg*DI + d] = silu_f(acc);
    }
}

// ================= phase PA: proj + local chunk scan =================
__device__ __forceinline__ void dev_PA(int u, int t, float* shm,
        const float* __restrict__ xc_t, const float* __restrict__ xpw,
        const float* __restrict__ dtw, const float* __restrict__ dtb,
        const float* __restrict__ A_logs, const float* __restrict__ Dsv,
        float* __restrict__ apb, float* __restrict__ xlb,
        float* __restrict__ Srb, float* __restrict__ CTb, float* __restrict__ yk)
{
    int k = u >> 8, cc = u & 255;
    int l0 = cc*CH;
    float* xt  = shm;          // 16 x 132
    float* Bt  = shm + 2112;   // [16][16]
    float* Ct  = shm + 2368;   // [16][16]
    float* dtt = shm + 2624;   // [4][16]
    __syncthreads();           // protect prior iteration's LDS
    #pragma unroll
    for(int q=0;q<4;q++){
        int lin = q*128 + t;
        int row = lin >> 5, c4 = lin & 31;
        int p = perm_in(k, l0 + row);
        float4 v = ((const float4*)(xc_t + (size_t)p*DI))[c4];
        *((float4*)(xt + row*132 + c4*4)) = v;
    }
    __syncthreads();
    {
        int lrow = t >> 3, c8 = t & 7;
        const float4* xrow = (const float4*)(xt + lrow*132);
        const float4* wb = (const float4*)(xpw + (size_t)k*36*DI);
        int c4r = (c8 < 4) ? (32+c8) : 32;
        float a0=0,a1=0,a2=0,a3=0,a4=0;
        for(int dd4=0; dd4<32; dd4++){
            float4 xv = xrow[dd4];
            float4 w0 = wb[(c8    )*32 + dd4];
            float4 w1 = wb[(8 +c8 )*32 + dd4];
            float4 w2 = wb[(16+c8 )*32 + dd4];
            float4 w3 = wb[(24+c8 )*32 + dd4];
            float4 w4v= wb[(c4r   )*32 + dd4];
            a0 += w0.x*xv.x + w0.y*xv.y + w0.z*xv.z + w0.w*xv.w;
            a1 += w1.x*xv.x + w1.y*xv.y + w1.z*xv.z + w1.w*xv.w;
            a2 += w2.x*xv.x + w2.y*xv.y + w2.z*xv.z + w2.w*xv.w;
            a3 += w3.x*xv.x + w3.y*xv.y + w3.z*xv.z + w3.w*xv.w;
            a4 += w4v.x*xv.x + w4v.y*xv.y + w4v.z*xv.z + w4v.w*xv.w;
        }
        if(c8 < 4) dtt[c8*16 + lrow] = a0;
        else       Bt[lrow*16 + (c8-4)] = a0;
        Bt[lrow*16 + 4 + c8] = a1;
        if(c8 < 4) Bt[lrow*16 + 12 + c8] = a2;
        else       Ct[lrow*16 + (c8-4)] = a2;
        Ct[lrow*16 + 4 + c8] = a3;
        if(c8 < 4) Ct[lrow*16 + 12 + c8] = a4;
    }
    __syncthreads();
    // persist C tile for phase C
    CTb[(size_t)u*256 + t]       = Ct[t];
    CTb[(size_t)u*256 + 128 + t] = Ct[128 + t];

    int d = t;
    float4 w4 = ((const float4*)dtw)[(size_t)k*DI + d];
    float  bb = dtb[k*DI + d];
    float  Dv = Dsv[k*DI + d];
    float A[NS];
    {
        const float4* ar = (const float4*)(A_logs + ((size_t)k*DI + d)*NS);
        #pragma unroll
        for(int q=0;q<4;q++){
            float4 a4 = ar[q];
            A[q*4+0] = -__expf(a4.x); A[q*4+1] = -__expf(a4.y);
            A[q*4+2] = -__expf(a4.z); A[q*4+3] = -__expf(a4.w);
        }
    }
    float xs[NS];
    float S = 0.f;
    #pragma unroll
    for(int n=0;n<NS;n++) xs[n] = 0.f;
    #pragma unroll
    for(int i=0;i<CH;i++){
        float dv = bb + w4.x*dtt[i] + w4.y*dtt[16+i] + w4.z*dtt[32+i] + w4.w*dtt[48+i];
        float delta = softplus_f(dv);
        S += delta;
        Srb[(size_t)u*2048 + i*128 + d] = S;
        float uu = xt[i*132 + d];
        float du = delta*uu;
        float yv = uu*Dv;
        const float* Bi = Bt + i*NS;
        const float* Ci = Ct + i*NS;
        #pragma unroll
        for(int n=0;n<NS;n++){
            float da = __expf(delta*A[n]);
            xs[n] = da*xs[n] + du*Bi[n];
            yv += xs[n]*Ci[n];
        }
        yk[(size_t)u*2048 + i*128 + d] = yv;   // local y
    }
    float* apd = apb + ((size_t)u*DI + d)*NS;
    float* xld = xlb + ((size_t)u*DI + d)*NS;
    #pragma unroll
    for(int q=0;q<4;q++){
        ((float4*)apd)[q] = make_float4(__expf(A[q*4]*S), __expf(A[q*4+1]*S),
                                        __expf(A[q*4+2]*S), __expf(A[q*4+3]*S));
        ((float4*)xld)[q] = make_float4(xs[q*4],xs[q*4+1],xs[q*4+2],xs[q*4+3]);
    }
}

// ================= phase B: sequential chunk combine =================
__device__ __forceinline__ void dev_B(int tid, float* __restrict__ apb,
                                      const float* __restrict__ xlb)
{
    int k2 = tid >> 11, rem = tid & 2047;     // rem = d*16+n
    size_t base = (size_t)k2*NC*2048 + rem;
    float run = 0.f;
    float a[8], xl[8];
    #pragma unroll
    for(int q=0;q<8;q++){ a[q] = apb[base + (size_t)q*2048]; xl[q] = xlb[base + (size_t)q*2048]; }
    for(int b=0; b<NC/8; b++){
        float a2[8], x2[8];
        if(b+1 < NC/8){
            #pragma unroll
            for(int q=0;q<8;q++){
                size_t off = base + (size_t)((b+1)*8+q)*2048;
                a2[q] = apb[off]; x2[q] = xlb[off];
            }
        }
        #pragma unroll
        for(int q=0;q<8;q++){
            size_t off = base + (size_t)(b*8+q)*2048;
            apb[off] = run;                 // becomes x_init
            run = a[q]*run + xl[q];
        }
        #pragma unroll
        for(int q=0;q<8;q++){ a[q] = a2[q]; xl[q] = x2[q]; }
    }
}

// ================= phase C: cross-chunk correction =================
__device__ __forceinline__ void dev_C(int u, int t, float* shm,
        const float* __restrict__ apb, const float* __restrict__ A_logs,
        const float* __restrict__ Srb, const float* __restrict__ CTb,
        float* __restrict__ yk)
{
    int k = u >> 8;
    int d = t;
    __syncthreads();    // protect prior iteration's LDS
    shm[t]       = CTb[(size_t)u*256 + t];
    shm[128 + t] = CTb[(size_t)u*256 + 128 + t];
    __syncthreads();
    float xi[NS], A[NS];
    {
        const float4* ir = (const float4*)(apb + ((size_t)u*DI + d)*NS);
        const float4* ar = (const float4*)(A_logs + ((size_t)k*DI + d)*NS);
        #pragma unroll
        for(int q=0;q<4;q++){
            float4 v = ir[q];
            xi[q*4]=v.x; xi[q*4+1]=v.y; xi[q*4+2]=v.z; xi[q*4+3]=v.w;
            float4 a4 = ar[q];
            A[q*4+0] = -__expf(a4.x); A[q*4+1] = -__expf(a4.y);
            A[q*4+2] = -__expf(a4.z); A[q*4+3] = -__expf(a4.w);
        }
    }
    #pragma unroll
    for(int i=0;i<CH;i++){
        size_t off = (size_t)u*2048 + i*128 + d;
        float Sr = Srb[off];
        const float* Ci = shm + i*NS;
        float corr = 0.f;
        #pragma unroll
        for(int n=0;n<NS;n++) corr += Ci[n]*__expf(A[n]*Sr)*xi[n];
        yk[off] += corr;
    }
}

// ================= phase D: gather + LN + gate + out-proj =================
__device__ __forceinline__ void dev_D(int tile, int t, float* shm,
        const float* __restrict__ yk, const float* __restrict__ sz,
        const float* __restrict__ ln_g, const float* __restrict__ ln_b,
        const float* __restrict__ W_out, float* __restrict__ out)
{
    float* ms  = shm;
    float* po  = shm + 128;
    float* red = shm + 256;
    int o = t & 63, half = t >> 6;
    float4 wo[16];
    const float4* wr4 = (const float4*)(W_out + (size_t)o*DI + half*64);
    #pragma unroll
    for(int q=0;q<16;q++) wo[q] = wr4[q];
    float g = ln_g[t], bc = ln_b[t];

    int p0 = tile*4;
    #pragma unroll
    for(int px=0; px<4; px++){
        int pg = p0 + px;
        int tp = ((pg&63)<<6) | (pg>>6);
        float y;
        y  = yk[((size_t)0*L + pg)*DI + t];
        y += yk[((size_t)1*L + tp)*DI + t];
        y += yk[((size_t)2*L + (L-1-pg))*DI + t];
        y += yk[((size_t)3*L + (L-1-tp))*DI + t];
        y += yk[((size_t)4*L + rankp(pg))*DI + t];
        y += yk[((size_t)5*L + rankp(L-1-pg))*DI + t];
        float s1 = y, s2 = y*y;
        #pragma unroll
        for(int m=1;m<64;m<<=1){ s1 += __shfl_xor(s1,m,64); s2 += __shfl_xor(s2,m,64); }
        __syncthreads();
        if((t&63)==0){ red[(t>>6)*2] = s1; red[(t>>6)*2+1] = s2; }
        __syncthreads();
        float mu  = (red[0]+red[2]) * (1.f/DI);
        float var = (red[1]+red[3]) * (1.f/DI) - mu*mu;
        float yh = (y-mu)*rsqrtf(var+1e-5f)*g + bc;
        ms[t] = yh * sz[(size_t)pg*DI + t];
        __syncthreads();
        float acc = 0.f;
        const float4* mr = (const float4*)(ms + half*64);
        #pragma unroll
        for(int q=0;q<16;q++){
            float4 xv = mr[q];
            acc += wo[q].x*xv.x + wo[q].y*xv.y + wo[q].z*xv.z + wo[q].w*xv.w;
        }
        po[half*64 + o] = acc;
        __syncthreads();
        if(t < 64) out[(size_t)pg*CM + t] = po[t] + po[64+t];
    }
}

// ================= cooperative mega-kernel (grid-size independent) =================
__global__ __launch_bounds__(128) void k_coop(const float* __restrict__ xc_t,
                                              const float* __restrict__ sz,
                                              const float* __restrict__ xpw,
                                              const float* __restrict__ dtw,
                                              const float* __restrict__ dtb,
                                              const float* __restrict__ A_logs,
                                              const float* __restrict__ Dsv,
                                              const float* __restrict__ ln_g,
                                              const float* __restrict__ ln_b,
                                              const float* __restrict__ W_out,
                                              float* __restrict__ apb,
                                              float* __restrict__ xlb,
                                              float* __restrict__ Srb,
                                              float* __restrict__ CTb,
                                              float* __restrict__ yk,
                                              float* __restrict__ out){
    cg::grid_group grid = cg::this_grid();
    __shared__ float shm[SHSZ];
    int t = threadIdx.x;
    for(int u = blockIdx.x; u < NU; u += gridDim.x)
        dev_PA(u, t, shm, xc_t, xpw, dtw, dtb, A_logs, Dsv, apb, xlb, Srb, CTb, yk);
    grid.sync();
    {
        int tid = blockIdx.x*128 + t;
        if(tid < KK*DI*NS) dev_B(tid, apb, xlb);
    }
    grid.sync();
    for(int u = blockIdx.x; u < NU; u += gridDim.x)
        dev_C(u, t, shm, apb, A_logs, Srb, CTb, yk);
    grid.sync();
    for(int tile = blockIdx.x; tile < L/4; tile += gridDim.x)
        dev_D(tile, t, shm, yk, sz, ln_g, ln_b, W_out, out);
}

// ================= fallback thin kernels =================
__global__ __launch_bounds__(128) void k_PA(const float* xc_t, const float* xpw,
        const float* dtw, const float* dtb, const float* A_logs, const float* Dsv,
        float* apb, float* xlb, float* Srb, float* CTb, float* yk){
    __shared__ float shm[SHSZ];
    for(int u = blockIdx.x; u < NU; u += gridDim.x)
        dev_PA(u, threadIdx.x, shm, xc_t, xpw, dtw, dtb, A_logs, Dsv, apb, xlb, Srb, CTb, yk);
}
__global__ __launch_bounds__(128) void k_B(float* apb, const float* xlb){
    int tid = blockIdx.x*128 + threadIdx.x;
    if(tid < KK*DI*NS) dev_B(tid, apb, xlb);
}
__global__ __launch_bounds__(128) void k_C(const float* apb, const float* A_logs,
        const float* Srb, const float* CTb, float* yk){
    __shared__ float shm[256];
    for(int u = blockIdx.x; u < NU; u += gridDim.x)
        dev_C(u, threadIdx.x, shm, apb, A_logs, Srb, CTb, yk);
}
__global__ __launch_bounds__(128) void k_D(const float* yk, const float* sz,
        const float* ln_g, const float* ln_b, const float* W_out, float* out){
    __shared__ float shm[260];
    for(int tile = blockIdx.x; tile < L/4; tile += gridDim.x)
        dev_D(tile, threadIdx.x, shm, yk, sz, ln_g, ln_b, W_out, out);
}

extern "C" void kernel_launch(void* const* d_in, const int* in_sizes, int n_in,
                              void* d_out, int out_size, void* d_ws, size_t ws_size,
                              hipStream_t stream) {
    const float* x      = (const float*)d_in[0];
    const float* W_in   = (const float*)d_in[1];
    const float* conv_w = (const float*)d_in[2];
    const float* conv_b = (const float*)d_in[3];
    const float* xpw    = (const float*)d_in[4];
    const float* dtw    = (const float*)d_in[5];
    const float* dtb    = (const float*)d_in[6];
    const float* A_logs = (const float*)d_in[7];
    const float* Dsv    = (const float*)d_in[8];
    const float* ln_g   = (const float*)d_in[9];
    const float* ln_b   = (const float*)d_in[10];
    const float* W_out  = (const float*)d_in[11];
    float* out = (float*)d_out;

    float* ws = (float*)d_ws;
    float* xc_t = ws;                           // L*DI
    float* sz   = xc_t + (size_t)L*DI;          // L*DI
    float* apb  = sz   + (size_t)L*DI;          // NU*DI*NS
    float* xlb  = apb  + (size_t)NU*DI*NS;      // NU*DI*NS
    float* Srb  = xlb  + (size_t)NU*DI*NS;      // NU*2048
    float* yk   = Srb  + (size_t)NU*2048;       // K*L*DI
    float* CTb  = yk   + (size_t)KK*L*DI;       // NU*256

    k_front<<<256, 256, 0, stream>>>(x, W_in, conv_w, conv_b, xc_t, sz);

    int coop_ok = 0;
    hipDeviceGetAttribute(&coop_ok, hipDeviceAttributeCooperativeLaunch, 0);
    int nb = 0;
    if(coop_ok)
        hipOccupancyMaxActiveBlocksPerMultiprocessor(&nb, k_coop, 128, 0);
    int grid = nb * 256;
    if(grid > NU) grid = NU;

    bool done = false;
    if(coop_ok && grid >= 256){
        void* args[] = {(void*)&xc_t, (void*)&sz, (void*)&xpw, (void*)&dtw, (void*)&dtb,
                        (void*)&A_logs, (void*)&Dsv, (void*)&ln_g, (void*)&ln_b,
                        (void*)&W_out, (void*)&apb, (void*)&xlb, (void*)&Srb,
                        (void*)&CTb, (void*)&yk, (void*)&out};
        hipError_t e = hipLaunchCooperativeKernel((void*)k_coop, dim3(grid), dim3(128),
                                                  args, 0, stream);
        done = (e == hipSuccess);
    }
    if(!done){
        k_PA<<<NU, 128, 0, stream>>>(xc_t, xpw, dtw, dtb, A_logs, Dsv, apb, xlb, Srb, CTb, yk);
        k_B <<<KK*DI*NS/128, 128, 0, stream>>>(apb, xlb);
        k_C <<<NU, 128, 0, stream>>>(apb, A_logs, Srb, CTb, yk);
        k_D <<<L/4, 128, 0, stream>>>(yk, sz, ln_g, ln_b, W_out, out);
    }
}

// Round 7
// 214.703 us; speedup vs baseline: 1.0247x; 1.0247x over previous
//
#include <hip/hip_runtime.h>
#include <math.h>

#define L    4096
#define DI   128
#define NS   16
#define KK   6
#define CM   64     // d_model
#define NC   256    // chunks per direction
#define CH   16     // steps per chunk
#define NU   (KK*NC)   // 1536 work units
#define SHSZ 2688

__device__ __forceinline__ float softplus_f(float x){
    return x > 20.f ? x : __logf(1.f + __expf(x));
}
__device__ __forceinline__ float silu_f(float x){
    return x / (1.f + __expf(-x));
}

// anti-diagonal rank of pixel p (closed form)
__device__ __forceinline__ int rankp(int p){
    int h = p >> 6, w = p & 63, s = h + w;
    int imin = s > 63 ? s - 63 : 0;
    int off = (s < 64) ? (s*(s+1))/2 : 4096 - ((127-s)*(128-s))/2;
    return off + (h - imin);
}
// inverse: pixel with anti-diagonal rank l
__device__ __forceinline__ int diag_pix(int l){
    if(l < 2080){
        int s = (int)((sqrtf(8.f*(float)l + 1.f) - 1.f)*0.5f);
        if((s+1)*(s+2)/2 <= l) s++;
        else if(s*(s+1)/2 > l) s--;
        int t = l - s*(s+1)/2;
        return t*64 + (s - t);
    } else {
        int r = 4096 - l;   // 1..2016
        int q = (int)((sqrtf(8.f*(float)r + 1.f) - 1.f)*0.5f);
        if(q*(q+1)/2 < r) q++;
        else if((q-1)*q/2 >= r) q--;
        int s = 127 - q;
        int off = 4096 - q*(q+1)/2;
        int t = l - off;
        int h = (s - 63) + t;
        return h*64 + (s - h);
    }
}
__device__ __forceinline__ int perm_in(int k, int l){
    switch(k){
        case 0: return l;
        case 1: return ((l&63)<<6) | (l>>6);
        case 2: return (L-1) - l;
        case 3: { int m = (L-1)-l; return ((m&63)<<6) | (m>>6); }
        case 4: return diag_pix(l);
        default: return diag_pix(l) ^ 63;
    }
}

// ================= front: in_proj + depthwise conv fused =================
__global__ __launch_bounds__(256) void k_front(const float* __restrict__ x,
                                               const float* __restrict__ W_in,
                                               const float* __restrict__ cw,
                                               const float* __restrict__ cb,
                                               float* __restrict__ xc_t,
                                               float* __restrict__ sz){
    int ty = blockIdx.x >> 4, tx = blockIdx.x & 15;
    int h0 = ty*4, w0 = tx*4;
    int t = threadIdx.x;
    __shared__ float xr[36*CM];
    __shared__ float xxs[36*DI];

    for(int lin = t; lin < 36*16; lin += 256){
        int px = lin >> 4, c4 = lin & 15;
        int hh = h0 - 1 + px/6, ww = w0 - 1 + px%6;
        float4 v = make_float4(0.f,0.f,0.f,0.f);
        if(hh >= 0 && hh < 64 && ww >= 0 && ww < 64)
            v = ((const float4*)(x + (size_t)(hh*64+ww)*CM))[c4];
        *((float4*)(xr + px*CM + c4*4)) = v;
    }
    __syncthreads();

    int o = t;
    float4 w[16];
    const float4* wrow = (const float4*)(W_in + (size_t)o*CM);
    #pragma unroll
    for(int q=0;q<16;q++) w[q] = wrow[q];
    for(int px=0; px<36; px++){
        const float4* xv4 = (const float4*)(xr + px*CM);
        float acc = 0.f;
        #pragma unroll
        for(int q=0;q<16;q++){
            float4 xv = xv4[q];
            acc += w[q].x*xv.x + w[q].y*xv.y + w[q].z*xv.z + w[q].w*xv.w;
        }
        if(o < DI) xxs[px*DI + o] = acc;
        else {
            int hr = px/6, wc = px%6;
            if(hr >= 1 && hr <= 4 && wc >= 1 && wc <= 4){
                int pg = (h0 + hr - 1)*64 + (w0 + wc - 1);
                sz[(size_t)pg*DI + (o-DI)] = silu_f(acc);
            }
        }
    }
    __syncthreads();

    int d = t & 127, ph = t >> 7;
    float cwr[9];
    #pragma unroll
    for(int j=0;j<9;j++) cwr[j] = cw[d*9+j];
    float cbd = cb[d];
    #pragma unroll
    for(int i=0;i<8;i++){
        int idx = ph*8 + i;
        int r = idx >> 2, c = idx & 3;
        float acc = cbd;
        #pragma unroll
        for(int dh=0; dh<3; dh++)
            #pragma unroll
            for(int dw=0; dw<3; dw++)
                acc += cwr[dh*3+dw] * xxs[((r+dh)*6 + (c+dw))*DI + d];
        int pg = (h0+r)*64 + (w0+c);
        xc_t[(size_t)pg*DI + d] = silu_f(acc);
    }
}

// ================= phase PA: proj + local chunk scan =================
__device__ __forceinline__ void dev_PA(int u, int t, float* shm,
        const float* __restrict__ xc_t, const float* __restrict__ xpw,
        const float* __restrict__ dtw, const float* __restrict__ dtb,
        const float* __restrict__ A_logs, const float* __restrict__ Dsv,
        float* __restrict__ apb, float* __restrict__ xlb,
        float* __restrict__ Srb, float* __restrict__ CTb, float* __restrict__ yk)
{
    int k = u >> 8, cc = u & 255;
    int l0 = cc*CH;
    float* xt  = shm;          // 16 x 132
    float* Bt  = shm + 2112;   // [16][16]
    float* Ct  = shm + 2368;   // [16][16]
    float* dtt = shm + 2624;   // [4][16]
    #pragma unroll
    for(int q=0;q<4;q++){
        int lin = q*128 + t;
        int row = lin >> 5, c4 = lin & 31;
        int p = perm_in(k, l0 + row);
        float4 v = ((const float4*)(xc_t + (size_t)p*DI))[c4];
        *((float4*)(xt + row*132 + c4*4)) = v;
    }
    __syncthreads();
    {
        int lrow = t >> 3, c8 = t & 7;
        const float4* xrow = (const float4*)(xt + lrow*132);
        const float4* wb = (const float4*)(xpw + (size_t)k*36*DI);
        int c4r = (c8 < 4) ? (32+c8) : 32;
        float a0=0,a1=0,a2=0,a3=0,a4=0;
        for(int dd4=0; dd4<32; dd4++){
            float4 xv = xrow[dd4];
            float4 w0 = wb[(c8    )*32 + dd4];
            float4 w1 = wb[(8 +c8 )*32 + dd4];
            float4 w2 = wb[(16+c8 )*32 + dd4];
            float4 w3 = wb[(24+c8 )*32 + dd4];
            float4 w4v= wb[(c4r   )*32 + dd4];
            a0 += w0.x*xv.x + w0.y*xv.y + w0.z*xv.z + w0.w*xv.w;
            a1 += w1.x*xv.x + w1.y*xv.y + w1.z*xv.z + w1.w*xv.w;
            a2 += w2.x*xv.x + w2.y*xv.y + w2.z*xv.z + w2.w*xv.w;
            a3 += w3.x*xv.x + w3.y*xv.y + w3.z*xv.z + w3.w*xv.w;
            a4 += w4v.x*xv.x + w4v.y*xv.y + w4v.z*xv.z + w4v.w*xv.w;
        }
        if(c8 < 4) dtt[c8*16 + lrow] = a0;
        else       Bt[lrow*16 + (c8-4)] = a0;
        Bt[lrow*16 + 4 + c8] = a1;
        if(c8 < 4) Bt[lrow*16 + 12 + c8] = a2;
        else       Ct[lrow*16 + (c8-4)] = a2;
        Ct[lrow*16 + 4 + c8] = a3;
        if(c8 < 4) Ct[lrow*16 + 12 + c8] = a4;
    }
    __syncthreads();
    // persist C tile for phase C
    CTb[(size_t)u*256 + t]       = Ct[t];
    CTb[(size_t)u*256 + 128 + t] = Ct[128 + t];

    int d = t;
    float4 w4 = ((const float4*)dtw)[(size_t)k*DI + d];
    float  bb = dtb[k*DI + d];
    float  Dv = Dsv[k*DI + d];
    float A[NS];
    {
        const float4* ar = (const float4*)(A_logs + ((size_t)k*DI + d)*NS);
        #pragma unroll
        for(int q=0;q<4;q++){
            float4 a4 = ar[q];
            A[q*4+0] = -__expf(a4.x); A[q*4+1] = -__expf(a4.y);
            A[q*4+2] = -__expf(a4.z); A[q*4+3] = -__expf(a4.w);
        }
    }
    float xs[NS];
    float S = 0.f;
    #pragma unroll
    for(int n=0;n<NS;n++) xs[n] = 0.f;
    #pragma unroll
    for(int i=0;i<CH;i++){
        float dv = bb + w4.x*dtt[i] + w4.y*dtt[16+i] + w4.z*dtt[32+i] + w4.w*dtt[48+i];
        float delta = softplus_f(dv);
        S += delta;
        Srb[(size_t)u*2048 + i*128 + d] = S;
        float uu = xt[i*132 + d];
        float du = delta*uu;
        float yv = uu*Dv;
        const float* Bi = Bt + i*NS;
        const float* Ci = Ct + i*NS;
        #pragma unroll
        for(int n=0;n<NS;n++){
            float da = __expf(delta*A[n]);
            xs[n] = da*xs[n] + du*Bi[n];
            yv += xs[n]*Ci[n];
        }
        yk[(size_t)u*2048 + i*128 + d] = yv;   // local y
    }
    float* apd = apb + ((size_t)u*DI + d)*NS;
    float* xld = xlb + ((size_t)u*DI + d)*NS;
    #pragma unroll
    for(int q=0;q<4;q++){
        ((float4*)apd)[q] = make_float4(__expf(A[q*4]*S), __expf(A[q*4+1]*S),
                                        __expf(A[q*4+2]*S), __expf(A[q*4+3]*S));
        ((float4*)xld)[q] = make_float4(xs[q*4],xs[q*4+1],xs[q*4+2],xs[q*4+3]);
    }
}

// ================= phase B: sequential chunk combine =================
__device__ __forceinline__ void dev_B(int tid, float* __restrict__ apb,
                                      const float* __restrict__ xlb)
{
    int k2 = tid >> 11, rem = tid & 2047;     // rem = d*16+n
    size_t base = (size_t)k2*NC*2048 + rem;
    float run = 0.f;
    float a[8], xl[8];
    #pragma unroll
    for(int q=0;q<8;q++){ a[q] = apb[base + (size_t)q*2048]; xl[q] = xlb[base + (size_t)q*2048]; }
    for(int b=0; b<NC/8; b++){
        float a2[8], x2[8];
        if(b+1 < NC/8){
            #pragma unroll
            for(int q=0;q<8;q++){
                size_t off = base + (size_t)((b+1)*8+q)*2048;
                a2[q] = apb[off]; x2[q] = xlb[off];
            }
        }
        #pragma unroll
        for(int q=0;q<8;q++){
            size_t off = base + (size_t)(b*8+q)*2048;
            apb[off] = run;                 // becomes x_init
            run = a[q]*run + xl[q];
        }
        #pragma unroll
        for(int q=0;q<8;q++){ a[q] = a2[q]; xl[q] = x2[q]; }
    }
}

// ================= phase C: cross-chunk correction =================
__device__ __forceinline__ void dev_C(int u, int t, float* shm,
        const float* __restrict__ apb, const float* __restrict__ A_logs,
        const float* __restrict__ Srb, const float* __restrict__ CTb,
        float* __restrict__ yk)
{
    int k = u >> 8;
    int d = t;
    shm[t]       = CTb[(size_t)u*256 + t];
    shm[128 + t] = CTb[(size_t)u*256 + 128 + t];
    __syncthreads();
    float xi[NS], A[NS];
    {
        const float4* ir = (const float4*)(apb + ((size_t)u*DI + d)*NS);
        const float4* ar = (const float4*)(A_logs + ((size_t)k*DI + d)*NS);
        #pragma unroll
        for(int q=0;q<4;q++){
            float4 v = ir[q];
            xi[q*4]=v.x; xi[q*4+1]=v.y; xi[q*4+2]=v.z; xi[q*4+3]=v.w;
            float4 a4 = ar[q];
            A[q*4+0] = -__expf(a4.x); A[q*4+1] = -__expf(a4.y);
            A[q*4+2] = -__expf(a4.z); A[q*4+3] = -__expf(a4.w);
        }
    }
    #pragma unroll
    for(int i=0;i<CH;i++){
        size_t off = (size_t)u*2048 + i*128 + d;
        float Sr = Srb[off];
        const float* Ci = shm + i*NS;
        float corr = 0.f;
        #pragma unroll
        for(int n=0;n<NS;n++) corr += Ci[n]*__expf(A[n]*Sr)*xi[n];
        yk[off] += corr;
    }
}

// ================= phase D: gather + LN + gate + out-proj =================
__device__ __forceinline__ void dev_D(int tile, int t, float* shm,
        const float* __restrict__ yk, const float* __restrict__ sz,
        const float* __restrict__ ln_g, const float* __restrict__ ln_b,
        const float* __restrict__ W_out, float* __restrict__ out)
{
    float* ms  = shm;
    float* po  = shm + 128;
    float* red = shm + 256;
    int o = t & 63, half = t >> 6;
    float4 wo[16];
    const float4* wr4 = (const float4*)(W_out + (size_t)o*DI + half*64);
    #pragma unroll
    for(int q=0;q<16;q++) wo[q] = wr4[q];
    float g = ln_g[t], bc = ln_b[t];

    int p0 = tile*4;
    #pragma unroll
    for(int px=0; px<4; px++){
        int pg = p0 + px;
        int tp = ((pg&63)<<6) | (pg>>6);
        float y;
        y  = yk[((size_t)0*L + pg)*DI + t];
        y += yk[((size_t)1*L + tp)*DI + t];
        y += yk[((size_t)2*L + (L-1-pg))*DI + t];
        y += yk[((size_t)3*L + (L-1-tp))*DI + t];
        y += yk[((size_t)4*L + rankp(pg))*DI + t];
        y += yk[((size_t)5*L + rankp(L-1-pg))*DI + t];
        float s1 = y, s2 = y*y;
        #pragma unroll
        for(int m=1;m<64;m<<=1){ s1 += __shfl_xor(s1,m,64); s2 += __shfl_xor(s2,m,64); }
        __syncthreads();
        if((t&63)==0){ red[(t>>6)*2] = s1; red[(t>>6)*2+1] = s2; }
        __syncthreads();
        float mu  = (red[0]+red[2]) * (1.f/DI);
        float var = (red[1]+red[3]) * (1.f/DI) - mu*mu;
        float yh = (y-mu)*rsqrtf(var+1e-5f)*g + bc;
        ms[t] = yh * sz[(size_t)pg*DI + t];
        __syncthreads();
        float acc = 0.f;
        const float4* mr = (const float4*)(ms + half*64);
        #pragma unroll
        for(int q=0;q<16;q++){
            float4 xv = mr[q];
            acc += wo[q].x*xv.x + wo[q].y*xv.y + wo[q].z*xv.z + wo[q].w*xv.w;
        }
        po[half*64 + o] = acc;
        __syncthreads();
        if(t < 64) out[(size_t)pg*CM + t] = po[t] + po[64+t];
    }
}

// ================= thin kernels (full occupancy each) =================
__global__ __launch_bounds__(128) void k_PA(const float* __restrict__ xc_t,
        const float* __restrict__ xpw, const float* __restrict__ dtw,
        const float* __restrict__ dtb, const float* __restrict__ A_logs,
        const float* __restrict__ Dsv, float* __restrict__ apb,
        float* __restrict__ xlb, float* __restrict__ Srb,
        float* __restrict__ CTb, float* __restrict__ yk){
    __shared__ float shm[SHSZ];
    dev_PA(blockIdx.x, threadIdx.x, shm, xc_t, xpw, dtw, dtb, A_logs, Dsv,
           apb, xlb, Srb, CTb, yk);
}
__global__ __launch_bounds__(128) void k_B(float* __restrict__ apb,
                                           const float* __restrict__ xlb){
    int tid = blockIdx.x*128 + threadIdx.x;
    if(tid < KK*DI*NS) dev_B(tid, apb, xlb);
}
__global__ __launch_bounds__(128) void k_C(const float* __restrict__ apb,
        const float* __restrict__ A_logs, const float* __restrict__ Srb,
        const float* __restrict__ CTb, float* __restrict__ yk){
    __shared__ float shm[256];
    dev_C(blockIdx.x, threadIdx.x, shm, apb, A_logs, Srb, CTb, yk);
}
__global__ __launch_bounds__(128) void k_D(const float* __restrict__ yk,
        const float* __restrict__ sz, const float* __restrict__ ln_g,
        const float* __restrict__ ln_b, const float* __restrict__ W_out,
        float* __restrict__ out){
    __shared__ float shm[260];
    dev_D(blockIdx.x, threadIdx.x, shm, yk, sz, ln_g, ln_b, W_out, out);
}

extern "C" void kernel_launch(void* const* d_in, const int* in_sizes, int n_in,
                              void* d_out, int out_size, void* d_ws, size_t ws_size,
                              hipStream_t stream) {
    const float* x      = (const float*)d_in[0];
    const float* W_in   = (const float*)d_in[1];
    const float* conv_w = (const float*)d_in[2];
    const float* conv_b = (const float*)d_in[3];
    const float* xpw    = (const float*)d_in[4];
    const float* dtw    = (const float*)d_in[5];
    const float* dtb    = (const float*)d_in[6];
    const float* A_logs = (const float*)d_in[7];
    const float* Dsv    = (const float*)d_in[8];
    const float* ln_g   = (const float*)d_in[9];
    const float* ln_b   = (const float*)d_in[10];
    const float* W_out  = (const float*)d_in[11];
    float* out = (float*)d_out;

    float* ws = (float*)d_ws;
    float* xc_t = ws;                           // L*DI
    float* sz   = xc_t + (size_t)L*DI;          // L*DI
    float* apb  = sz   + (size_t)L*DI;          // NU*DI*NS
    float* xlb  = apb  + (size_t)NU*DI*NS;      // NU*DI*NS
    float* Srb  = xlb  + (size_t)NU*DI*NS;      // NU*2048
    float* yk   = Srb  + (size_t)NU*2048;       // K*L*DI
    float* CTb  = yk   + (size_t)KK*L*DI;       // NU*256

    k_front<<<256, 256, 0, stream>>>(x, W_in, conv_w, conv_b, xc_t, sz);
    k_PA   <<<NU, 128, 0, stream>>>(xc_t, xpw, dtw, dtb, A_logs, Dsv, apb, xlb, Srb, CTb, yk);
    k_B    <<<KK*DI*NS/128, 128, 0, stream>>>(apb, xlb);
    k_C    <<<NU, 128, 0, stream>>>(apb, A_logs, Srb, CTb, yk);
    k_D    <<<L/4, 128, 0, stream>>>(yk, sz, ln_g, ln_b, W_out, out);
}

// Round 8
// 208.865 us; speedup vs baseline: 1.0534x; 1.0280x over previous
//
#include <hip/hip_runtime.h>
#include <math.h>

#define L    4096
#define DI   128
#define NS   16
#define KK   6
#define CM   64     // d_model
#define NC   512    // chunks per direction
#define CH   8      // steps per chunk
#define NU   (KK*NC)   // 3072 scan work units

__device__ __forceinline__ float softplus_f(float x){
    return x > 20.f ? x : __logf(1.f + __expf(x));
}
__device__ __forceinline__ float silu_f(float x){
    return x / (1.f + __expf(-x));
}

// anti-diagonal rank of pixel p (closed form)
__device__ __forceinline__ int rankp(int p){
    int h = p >> 6, w = p & 63, s = h + w;
    int imin = s > 63 ? s - 63 : 0;
    int off = (s < 64) ? (s*(s+1))/2 : 4096 - ((127-s)*(128-s))/2;
    return off + (h - imin);
}
// inverse: pixel with anti-diagonal rank l
__device__ __forceinline__ int diag_pix(int l){
    if(l < 2080){
        int s = (int)((sqrtf(8.f*(float)l + 1.f) - 1.f)*0.5f);
        if((s+1)*(s+2)/2 <= l) s++;
        else if(s*(s+1)/2 > l) s--;
        int t = l - s*(s+1)/2;
        return t*64 + (s - t);
    } else {
        int r = 4096 - l;   // 1..2016
        int q = (int)((sqrtf(8.f*(float)r + 1.f) - 1.f)*0.5f);
        if(q*(q+1)/2 < r) q++;
        else if((q-1)*q/2 >= r) q--;
        int s = 127 - q;
        int off = 4096 - q*(q+1)/2;
        int t = l - off;
        int h = (s - 63) + t;
        return h*64 + (s - h);
    }
}
__device__ __forceinline__ int perm_in(int k, int l){
    switch(k){
        case 0: return l;
        case 1: return ((l&63)<<6) | (l>>6);
        case 2: return (L-1) - l;
        case 3: { int m = (L-1)-l; return ((m&63)<<6) | (m>>6); }
        case 4: return diag_pix(l);
        default: return diag_pix(l) ^ 63;
    }
}

// ================= front: in_proj + depthwise conv fused =================
__global__ __launch_bounds__(256) void k_front(const float* __restrict__ x,
                                               const float* __restrict__ W_in,
                                               const float* __restrict__ cw,
                                               const float* __restrict__ cb,
                                               float* __restrict__ xc_t,
                                               float* __restrict__ sz){
    int ty = blockIdx.x >> 4, tx = blockIdx.x & 15;
    int h0 = ty*4, w0 = tx*4;
    int t = threadIdx.x;
    __shared__ float xr[36*CM];
    __shared__ float xxs[36*DI];

    for(int lin = t; lin < 36*16; lin += 256){
        int px = lin >> 4, c4 = lin & 15;
        int hh = h0 - 1 + px/6, ww = w0 - 1 + px%6;
        float4 v = make_float4(0.f,0.f,0.f,0.f);
        if(hh >= 0 && hh < 64 && ww >= 0 && ww < 64)
            v = ((const float4*)(x + (size_t)(hh*64+ww)*CM))[c4];
        *((float4*)(xr + px*CM + c4*4)) = v;
    }
    __syncthreads();

    int o = t;
    float4 w[16];
    const float4* wrow = (const float4*)(W_in + (size_t)o*CM);
    #pragma unroll
    for(int q=0;q<16;q++) w[q] = wrow[q];
    for(int px=0; px<36; px++){
        const float4* xv4 = (const float4*)(xr + px*CM);
        float acc = 0.f;
        #pragma unroll
        for(int q=0;q<16;q++){
            float4 xv = xv4[q];
            acc += w[q].x*xv.x + w[q].y*xv.y + w[q].z*xv.z + w[q].w*xv.w;
        }
        if(o < DI) xxs[px*DI + o] = acc;
        else {
            int hr = px/6, wc = px%6;
            if(hr >= 1 && hr <= 4 && wc >= 1 && wc <= 4){
                int pg = (h0 + hr - 1)*64 + (w0 + wc - 1);
                sz[(size_t)pg*DI + (o-DI)] = silu_f(acc);
            }
        }
    }
    __syncthreads();

    int d = t & 127, ph = t >> 7;
    float cwr[9];
    #pragma unroll
    for(int j=0;j<9;j++) cwr[j] = cw[d*9+j];
    float cbd = cb[d];
    #pragma unroll
    for(int i=0;i<8;i++){
        int idx = ph*8 + i;
        int r = idx >> 2, c = idx & 3;
        float acc = cbd;
        #pragma unroll
        for(int dh=0; dh<3; dh++)
            #pragma unroll
            for(int dw=0; dw<3; dw++)
                acc += cwr[dh*3+dw] * xxs[((r+dh)*6 + (c+dw))*DI + d];
        int pg = (h0+r)*64 + (w0+c);
        xc_t[(size_t)pg*DI + d] = silu_f(acc);
    }
}

// ================= proj: 64-l tiles -> dts/BT/CT =================
#define XT_S 132
__global__ __launch_bounds__(256) void k_proj(const float* __restrict__ xc_t,
                                              const float* __restrict__ xpw,   // (K,36,DI)
                                              float* __restrict__ dts,         // (K,4,L)
                                              float* __restrict__ BT,          // (K,L,NS)
                                              float* __restrict__ CT){         // (K,L,NS)
    int k  = blockIdx.x >> 6;
    int l0 = (blockIdx.x & 63) * 64;
    int t  = threadIdx.x;
    __shared__ float xt[64*XT_S];
    #pragma unroll
    for(int q=0;q<8;q++){
        int lin = q*256 + t;
        int row = lin >> 5, col4 = lin & 31;
        int p = perm_in(k, l0+row);
        float4 v = ((const float4*)(xc_t + (size_t)p*DI))[col4];
        *((float4*)(xt + row*XT_S + col4*4)) = v;
    }
    __syncthreads();
    int l = t & 63, c0 = (t>>6)*9;
    const float* xr = xt + l*XT_S;
    float acc[9];
    #pragma unroll
    for(int j=0;j<9;j++) acc[j] = 0.f;
    const float4* wbase = (const float4*)(xpw + (size_t)k*36*DI);
    for(int dd4=0; dd4<32; dd4++){
        float4 xv = *((const float4*)(xr + dd4*4));
        #pragma unroll
        for(int j=0;j<9;j++){
            float4 wv = wbase[(c0+j)*32 + dd4];
            acc[j] += wv.x*xv.x + wv.y*xv.y + wv.z*xv.z + wv.w*xv.w;
        }
    }
    #pragma unroll
    for(int j=0;j<9;j++){
        int c = c0 + j;
        if(c < 4)        dts[((size_t)k*4 + c)*L + l0 + l] = acc[j];
        else if(c < 20)  BT[((size_t)k*L + l0 + l)*NS + (c-4)]  = acc[j];
        else             CT[((size_t)k*L + l0 + l)*NS + (c-20)] = acc[j];
    }
}

// ================= PA: local chunk scan (CH=8) =================
__global__ __launch_bounds__(128) void k_PA(const float* __restrict__ xc_t,
                                            const float* __restrict__ dts,
                                            const float* __restrict__ BT,
                                            const float* __restrict__ CT,
                                            const float* __restrict__ dtw,   // (K,DI,4)
                                            const float* __restrict__ dtb,   // (K,DI)
                                            const float* __restrict__ A_logs,// (K*DI,NS)
                                            const float* __restrict__ Dsv,   // (K*DI)
                                            float* __restrict__ apb,         // (K,NC,DI,NS)
                                            float* __restrict__ xlb,
                                            float* __restrict__ yk){         // (K,L,DI)
    int u = blockIdx.x;
    int k = u >> 9, cc = u & (NC-1);
    int l0 = cc*CH;
    int t = threadIdx.x;

    __shared__ float xt[CH*132];   // 8 rows padded
    __shared__ float Bt[CH*NS];    // 128
    __shared__ float Ct[CH*NS];    // 128
    __shared__ float dtt[4*CH];    // 32

    #pragma unroll
    for(int q=0;q<2;q++){
        int lin = q*128 + t;
        int row = lin >> 5, c4 = lin & 31;
        int p = perm_in(k, l0 + row);
        float4 v = ((const float4*)(xc_t + (size_t)p*DI))[c4];
        *((float4*)(xt + row*132 + c4*4)) = v;
    }
    if(t < 32)       ((float4*)Bt)[t]    = ((const float4*)(BT + ((size_t)k*L + l0)*NS))[t];
    else if(t < 64)  ((float4*)Ct)[t-32] = ((const float4*)(CT + ((size_t)k*L + l0)*NS))[t-32];
    else if(t < 96){ int j = t-64; int r = j>>3, i = j&7;
                     dtt[r*CH + i] = dts[((size_t)k*4 + r)*L + l0 + i]; }
    __syncthreads();

    int d = t;
    float4 w4 = ((const float4*)dtw)[(size_t)k*DI + d];
    float  bb = dtb[k*DI + d];
    float  Dv = Dsv[k*DI + d];
    float A[NS];
    {
        const float4* ar = (const float4*)(A_logs + ((size_t)k*DI + d)*NS);
        #pragma unroll
        for(int q=0;q<4;q++){
            float4 a4 = ar[q];
            A[q*4+0] = -__expf(a4.x); A[q*4+1] = -__expf(a4.y);
            A[q*4+2] = -__expf(a4.z); A[q*4+3] = -__expf(a4.w);
        }
    }
    float xs[NS];
    float S = 0.f;
    #pragma unroll
    for(int n=0;n<NS;n++) xs[n] = 0.f;
    #pragma unroll
    for(int i=0;i<CH;i++){
        float dv = bb + w4.x*dtt[i] + w4.y*dtt[CH+i] + w4.z*dtt[2*CH+i] + w4.w*dtt[3*CH+i];
        float delta = softplus_f(dv);
        S += delta;
        float uu = xt[i*132 + d];
        float du = delta*uu;
        float yv = uu*Dv;
        const float* Bi = Bt + i*NS;
        const float* Ci = Ct + i*NS;
        #pragma unroll
        for(int n=0;n<NS;n++){
            float da = __expf(delta*A[n]);
            xs[n] = da*xs[n] + du*Bi[n];
            yv += xs[n]*Ci[n];
        }
        yk[(size_t)u*(CH*DI) + i*DI + d] = yv;   // local y
    }
    float* apd = apb + ((size_t)u*DI + d)*NS;
    float* xld = xlb + ((size_t)u*DI + d)*NS;
    #pragma unroll
    for(int q=0;q<4;q++){
        ((float4*)apd)[q] = make_float4(__expf(A[q*4]*S), __expf(A[q*4+1]*S),
                                        __expf(A[q*4+2]*S), __expf(A[q*4+3]*S));
        ((float4*)xld)[q] = make_float4(xs[q*4],xs[q*4+1],xs[q*4+2],xs[q*4+3]);
    }
}

// ================= B: sequential chunk combine (chain = NC) =================
__global__ __launch_bounds__(128) void k_B(float* __restrict__ apb,
                                           const float* __restrict__ xlb){
    int tid = blockIdx.x*128 + threadIdx.x;   // K*DI*NS = 12288
    if(tid >= KK*DI*NS) return;
    int k2 = tid >> 11, rem = tid & 2047;     // rem = d*16+n
    size_t base = (size_t)k2*NC*2048 + rem;
    float run = 0.f;
    float a[8], xl[8];
    #pragma unroll
    for(int q=0;q<8;q++){ a[q] = apb[base + (size_t)q*2048]; xl[q] = xlb[base + (size_t)q*2048]; }
    for(int b=0; b<NC/8; b++){
        float a2[8], x2[8];
        if(b+1 < NC/8){
            #pragma unroll
            for(int q=0;q<8;q++){
                size_t off = base + (size_t)((b+1)*8+q)*2048;
                a2[q] = apb[off]; x2[q] = xlb[off];
            }
        }
        #pragma unroll
        for(int q=0;q<8;q++){
            size_t off = base + (size_t)(b*8+q)*2048;
            apb[off] = run;                 // becomes x_init
            run = a[q]*run + xl[q];
        }
        #pragma unroll
        for(int q=0;q<8;q++){ a[q] = a2[q]; xl[q] = x2[q]; }
    }
}

// ================= C: cross-chunk correction (recompute delta-prefix) =================
__global__ __launch_bounds__(128) void k_C(const float* __restrict__ apb,   // x_init
                                           const float* __restrict__ dts,
                                           const float* __restrict__ CT,
                                           const float* __restrict__ dtw,
                                           const float* __restrict__ dtb,
                                           const float* __restrict__ A_logs,
                                           float* __restrict__ yk){
    int u = blockIdx.x;
    int k = u >> 9, cc = u & (NC-1);
    int l0 = cc*CH;
    int t = threadIdx.x;

    __shared__ float Ct[CH*NS];    // 128
    __shared__ float dtt[4*CH];    // 32
    if(t < 32)       ((float4*)Ct)[t] = ((const float4*)(CT + ((size_t)k*L + l0)*NS))[t];
    else if(t < 64){ int j = t-32; int r = j>>3, i = j&7;
                     dtt[r*CH + i] = dts[((size_t)k*4 + r)*L + l0 + i]; }
    __syncthreads();

    int d = t;
    float4 w4 = ((const float4*)dtw)[(size_t)k*DI + d];
    float  bb = dtb[k*DI + d];
    float xi[NS], A[NS];
    {
        const float4* ir = (const float4*)(apb + ((size_t)u*DI + d)*NS);
        const float4* ar = (const float4*)(A_logs + ((size_t)k*DI + d)*NS);
        #pragma unroll
        for(int q=0;q<4;q++){
            float4 v = ir[q];
            xi[q*4]=v.x; xi[q*4+1]=v.y; xi[q*4+2]=v.z; xi[q*4+3]=v.w;
            float4 a4 = ar[q];
            A[q*4+0] = -__expf(a4.x); A[q*4+1] = -__expf(a4.y);
            A[q*4+2] = -__expf(a4.z); A[q*4+3] = -__expf(a4.w);
        }
    }
    float S = 0.f;
    #pragma unroll
    for(int i=0;i<CH;i++){
        float dv = bb + w4.x*dtt[i] + w4.y*dtt[CH+i] + w4.z*dtt[2*CH+i] + w4.w*dtt[3*CH+i];
        S += softplus_f(dv);
        const float* Ci = Ct + i*NS;
        float corr = 0.f;
        #pragma unroll
        for(int n=0;n<NS;n++) corr += Ci[n]*__expf(A[n]*S)*xi[n];
        yk[(size_t)u*(CH*DI) + i*DI + d] += corr;
    }
}

// ================= D: gather 6 dirs + LN + gate + out-proj (2 px/block) =================
__global__ __launch_bounds__(128) void k_D(const float* __restrict__ yk,
                                           const float* __restrict__ sz,
                                           const float* __restrict__ ln_g,
                                           const float* __restrict__ ln_b,
                                           const float* __restrict__ W_out, // (CM,DI)
                                           float* __restrict__ out){        // (L,CM)
    __shared__ float ms[DI];
    __shared__ float po[DI];
    __shared__ float red[4];
    int t = threadIdx.x;
    int o = t & 63, half = t >> 6;
    float4 wo[16];
    const float4* wr4 = (const float4*)(W_out + (size_t)o*DI + half*64);
    #pragma unroll
    for(int q=0;q<16;q++) wo[q] = wr4[q];
    float g = ln_g[t], bc = ln_b[t];

    int p0 = blockIdx.x*2;
    #pragma unroll
    for(int px=0; px<2; px++){
        int pg = p0 + px;
        int tp = ((pg&63)<<6) | (pg>>6);
        float y;
        y  = yk[((size_t)0*L + pg)*DI + t];
        y += yk[((size_t)1*L + tp)*DI + t];
        y += yk[((size_t)2*L + (L-1-pg))*DI + t];
        y += yk[((size_t)3*L + (L-1-tp))*DI + t];
        y += yk[((size_t)4*L + rankp(pg))*DI + t];
        y += yk[((size_t)5*L + rankp(L-1-pg))*DI + t];
        float s1 = y, s2 = y*y;
        #pragma unroll
        for(int m=1;m<64;m<<=1){ s1 += __shfl_xor(s1,m,64); s2 += __shfl_xor(s2,m,64); }
        __syncthreads();
        if((t&63)==0){ red[(t>>6)*2] = s1; red[(t>>6)*2+1] = s2; }
        __syncthreads();
        float mu  = (red[0]+red[2]) * (1.f/DI);
        float var = (red[1]+red[3]) * (1.f/DI) - mu*mu;
        float yh = (y-mu)*rsqrtf(var+1e-5f)*g + bc;
        ms[t] = yh * sz[(size_t)pg*DI + t];
        __syncthreads();
        float acc = 0.f;
        const float4* mr = (const float4*)(ms + half*64);
        #pragma unroll
        for(int q=0;q<16;q++){
            float4 xv = mr[q];
            acc += wo[q].x*xv.x + wo[q].y*xv.y + wo[q].z*xv.z + wo[q].w*xv.w;
        }
        po[half*64 + o] = acc;
        __syncthreads();
        if(t < 64) out[(size_t)pg*CM + t] = po[t] + po[64+t];
    }
}

extern "C" void kernel_launch(void* const* d_in, const int* in_sizes, int n_in,
                              void* d_out, int out_size, void* d_ws, size_t ws_size,
                              hipStream_t stream) {
    const float* x      = (const float*)d_in[0];
    const float* W_in   = (const float*)d_in[1];
    const float* conv_w = (const float*)d_in[2];
    const float* conv_b = (const float*)d_in[3];
    const float* xpw    = (const float*)d_in[4];
    const float* dtw    = (const float*)d_in[5];
    const float* dtb    = (const float*)d_in[6];
    const float* A_logs = (const float*)d_in[7];
    const float* Dsv    = (const float*)d_in[8];
    const float* ln_g   = (const float*)d_in[9];
    const float* ln_b   = (const float*)d_in[10];
    const float* W_out  = (const float*)d_in[11];
    float* out = (float*)d_out;

    float* ws = (float*)d_ws;
    float* xc_t = ws;                           // L*DI
    float* sz   = xc_t + (size_t)L*DI;          // L*DI
    float* dts  = sz   + (size_t)L*DI;          // K*4*L
    float* BT   = dts  + (size_t)KK*4*L;        // K*L*NS
    float* CT   = BT   + (size_t)KK*L*NS;       // K*L*NS
    float* apb  = CT   + (size_t)KK*L*NS;       // NU*DI*NS
    float* xlb  = apb  + (size_t)NU*DI*NS;      // NU*DI*NS
    float* yk   = xlb  + (size_t)NU*DI*NS;      // K*L*DI

    k_front<<<256, 256, 0, stream>>>(x, W_in, conv_w, conv_b, xc_t, sz);
    k_proj <<<KK*64, 256, 0, stream>>>(xc_t, xpw, dts, BT, CT);
    k_PA   <<<NU, 128, 0, stream>>>(xc_t, dts, BT, CT, dtw, dtb, A_logs, Dsv, apb, xlb, yk);
    k_B    <<<96, 128, 0, stream>>>(apb, xlb);
    k_C    <<<NU, 128, 0, stream>>>(apb, dts, CT, dtw, dtb, A_logs, yk);
    k_D    <<<L/2, 128, 0, stream>>>(yk, sz, ln_g, ln_b, W_out, out);
}

// Round 9
// 196.623 us; speedup vs baseline: 1.1190x; 1.0623x over previous
//
#include <hip/hip_runtime.h>
#include <math.h>

#define L    4096
#define DI   128
#define NS   16
#define KK   6
#define CM   64     // d_model
#define NC   256    // chunks per direction
#define CH   16     // steps per chunk
#define NU   (KK*NC)   // 1536 scan work units

__device__ __forceinline__ float softplus_f(float x){
    return x > 20.f ? x : __logf(1.f + __expf(x));
}
__device__ __forceinline__ float silu_f(float x){
    return x / (1.f + __expf(-x));
}

// anti-diagonal rank of pixel p (closed form)
__device__ __forceinline__ int rankp(int p){
    int h = p >> 6, w = p & 63, s = h + w;
    int imin = s > 63 ? s - 63 : 0;
    int off = (s < 64) ? (s*(s+1))/2 : 4096 - ((127-s)*(128-s))/2;
    return off + (h - imin);
}
// inverse: pixel with anti-diagonal rank l
__device__ __forceinline__ int diag_pix(int l){
    if(l < 2080){
        int s = (int)((sqrtf(8.f*(float)l + 1.f) - 1.f)*0.5f);
        if((s+1)*(s+2)/2 <= l) s++;
        else if(s*(s+1)/2 > l) s--;
        int t = l - s*(s+1)/2;
        return t*64 + (s - t);
    } else {
        int r = 4096 - l;   // 1..2016
        int q = (int)((sqrtf(8.f*(float)r + 1.f) - 1.f)*0.5f);
        if(q*(q+1)/2 < r) q++;
        else if((q-1)*q/2 >= r) q--;
        int s = 127 - q;
        int off = 4096 - q*(q+1)/2;
        int t = l - off;
        int h = (s - 63) + t;
        return h*64 + (s - h);
    }
}
__device__ __forceinline__ int perm_in(int k, int l){
    switch(k){
        case 0: return l;
        case 1: return ((l&63)<<6) | (l>>6);
        case 2: return (L-1) - l;
        case 3: { int m = (L-1)-l; return ((m&63)<<6) | (m>>6); }
        case 4: return diag_pix(l);
        default: return diag_pix(l) ^ 63;
    }
}

// ================= front: in_proj + depthwise conv fused =================
__global__ __launch_bounds__(256) void k_front(const float* __restrict__ x,
                                               const float* __restrict__ W_in,
                                               const float* __restrict__ cw,
                                               const float* __restrict__ cb,
                                               float* __restrict__ xc_t,
                                               float* __restrict__ sz){
    int ty = blockIdx.x >> 4, tx = blockIdx.x & 15;
    int h0 = ty*4, w0 = tx*4;
    int t = threadIdx.x;
    __shared__ float xr[36*CM];
    __shared__ float xxs[36*DI];

    for(int lin = t; lin < 36*16; lin += 256){
        int px = lin >> 4, c4 = lin & 15;
        int hh = h0 - 1 + px/6, ww = w0 - 1 + px%6;
        float4 v = make_float4(0.f,0.f,0.f,0.f);
        if(hh >= 0 && hh < 64 && ww >= 0 && ww < 64)
            v = ((const float4*)(x + (size_t)(hh*64+ww)*CM))[c4];
        *((float4*)(xr + px*CM + c4*4)) = v;
    }
    __syncthreads();

    int o = t;
    float4 w[16];
    const float4* wrow = (const float4*)(W_in + (size_t)o*CM);
    #pragma unroll
    for(int q=0;q<16;q++) w[q] = wrow[q];
    for(int px=0; px<36; px++){
        const float4* xv4 = (const float4*)(xr + px*CM);
        float acc = 0.f;
        #pragma unroll
        for(int q=0;q<16;q++){
            float4 xv = xv4[q];
            acc += w[q].x*xv.x + w[q].y*xv.y + w[q].z*xv.z + w[q].w*xv.w;
        }
        if(o < DI) xxs[px*DI + o] = acc;
        else {
            int hr = px/6, wc = px%6;
            if(hr >= 1 && hr <= 4 && wc >= 1 && wc <= 4){
                int pg = (h0 + hr - 1)*64 + (w0 + wc - 1);
                sz[(size_t)pg*DI + (o-DI)] = silu_f(acc);
            }
        }
    }
    __syncthreads();

    int d = t & 127, ph = t >> 7;
    float cwr[9];
    #pragma unroll
    for(int j=0;j<9;j++) cwr[j] = cw[d*9+j];
    float cbd = cb[d];
    #pragma unroll
    for(int i=0;i<8;i++){
        int idx = ph*8 + i;
        int r = idx >> 2, c = idx & 3;
        float acc = cbd;
        #pragma unroll
        for(int dh=0; dh<3; dh++)
            #pragma unroll
            for(int dw=0; dw<3; dw++)
                acc += cwr[dh*3+dw] * xxs[((r+dh)*6 + (c+dw))*DI + d];
        int pg = (h0+r)*64 + (w0+c);
        xc_t[(size_t)pg*DI + d] = silu_f(acc);
    }
}

// ================= S1: proj (fused) + aggregate-only scan =================
// block = chunk u; 256 threads. proj: (l = t&15, 3 c's). scan: (d = t>>1, nh = t&1, 8 states)
__global__ __launch_bounds__(256) void k_S1(const float* __restrict__ xc_t,
                                            const float* __restrict__ xpw,   // (K,36,DI)
                                            const float* __restrict__ dtw,   // (K,DI,4)
                                            const float* __restrict__ dtb,   // (K,DI)
                                            const float* __restrict__ A_logs,// (K*DI,NS)
                                            float* __restrict__ apb,         // (K,NC,DI,NS)
                                            float* __restrict__ xlb,
                                            float* __restrict__ bcd){        // (NU,576)
    int u = blockIdx.x;
    int k = u >> 8, cc = u & (NC-1);
    int l0 = cc*CH;
    int t = threadIdx.x;

    __shared__ float xt[CH*132];   // 2112
    __shared__ float Bt[256];      // [l][16]
    __shared__ float Ct[256];
    __shared__ float dtt[64];      // [4][16]

    #pragma unroll
    for(int q=0;q<2;q++){
        int lin = q*256 + t;
        int row = lin >> 5, c4 = lin & 31;
        int p = perm_in(k, l0 + row);
        float4 v = ((const float4*)(xc_t + (size_t)p*DI))[c4];
        *((float4*)(xt + row*132 + c4*4)) = v;
    }
    __syncthreads();

    // proj: thread (l = t&15, cg = t>>4), c = 3*cg+j
    {
        int l = t & 15, cg = t >> 4;
        const float4* xrow = (const float4*)(xt + l*132);
        const float4* wb = (const float4*)(xpw + (size_t)k*36*DI);
        int cbase = 3*cg;
        float a0=0.f, a1=0.f, a2=0.f;
        int c0 = cbase   < 36 ? cbase   : 35;
        int c1 = cbase+1 < 36 ? cbase+1 : 35;
        int c2 = cbase+2 < 36 ? cbase+2 : 35;
        for(int dd4=0; dd4<32; dd4++){
            float4 xv = xrow[dd4];
            float4 w0 = wb[c0*32 + dd4];
            float4 w1 = wb[c1*32 + dd4];
            float4 w2 = wb[c2*32 + dd4];
            a0 += w0.x*xv.x + w0.y*xv.y + w0.z*xv.z + w0.w*xv.w;
            a1 += w1.x*xv.x + w1.y*xv.y + w1.z*xv.z + w1.w*xv.w;
            a2 += w2.x*xv.x + w2.y*xv.y + w2.z*xv.z + w2.w*xv.w;
        }
        float av[3] = {a0, a1, a2};
        #pragma unroll
        for(int j=0;j<3;j++){
            int c = cbase + j;
            if(c < 4)        dtt[c*16 + l] = av[j];
            else if(c < 20)  Bt[l*16 + (c-4)]  = av[j];
            else if(c < 36)  Ct[l*16 + (c-20)] = av[j];
        }
    }
    __syncthreads();

    // persist tiles for S2 (verbatim)
    {
        size_t b0 = (size_t)u*576;
        bcd[b0 + t]       = (t < 64) ? dtt[t]     : Bt[t-64];
        bcd[b0 + 256 + t] = (t < 64) ? Bt[192+t]  : Ct[t-64];
        if(t < 64) bcd[b0 + 512 + t] = Ct[192+t];
    }

    // scan pass 1 (no y): d = t>>1, nh = t&1
    int d = t >> 1, nh = t & 1;
    float4 w4 = ((const float4*)dtw)[(size_t)k*DI + d];
    float  bb = dtb[k*DI + d];
    float A[8];
    {
        const float4* ar = (const float4*)(A_logs + ((size_t)k*DI + d)*NS + nh*8);
        #pragma unroll
        for(int q=0;q<2;q++){
            float4 a4 = ar[q];
            A[q*4+0] = -__expf(a4.x); A[q*4+1] = -__expf(a4.y);
            A[q*4+2] = -__expf(a4.z); A[q*4+3] = -__expf(a4.w);
        }
    }
    float xs[8];
    float S = 0.f;
    #pragma unroll
    for(int n=0;n<8;n++) xs[n] = 0.f;
    #pragma unroll
    for(int i=0;i<CH;i++){
        float dv = bb + w4.x*dtt[i] + w4.y*dtt[16+i] + w4.z*dtt[32+i] + w4.w*dtt[48+i];
        float delta = softplus_f(dv);
        S += delta;
        float uu = xt[i*132 + d];
        float du = delta*uu;
        const float* Bi = Bt + i*16 + nh*8;
        #pragma unroll
        for(int n=0;n<8;n++){
            float da = __expf(delta*A[n]);
            xs[n] = da*xs[n] + du*Bi[n];
        }
    }
    float* apd = apb + (size_t)u*2048 + d*16 + nh*8;
    float* xld = xlb + (size_t)u*2048 + d*16 + nh*8;
    #pragma unroll
    for(int q=0;q<2;q++){
        ((float4*)apd)[q] = make_float4(__expf(A[q*4]*S), __expf(A[q*4+1]*S),
                                        __expf(A[q*4+2]*S), __expf(A[q*4+3]*S));
        ((float4*)xld)[q] = make_float4(xs[q*4], xs[q*4+1], xs[q*4+2], xs[q*4+3]);
    }
}

// ================= B: sequential chunk combine (chain = NC, in registers) =================
__global__ __launch_bounds__(128) void k_B(float* __restrict__ apb,
                                           const float* __restrict__ xlb){
    int tid = blockIdx.x*128 + threadIdx.x;   // K*DI*NS = 12288
    if(tid >= KK*DI*NS) return;
    int k2 = tid >> 11, rem = tid & 2047;     // rem = d*16+n
    size_t base = (size_t)k2*NC*2048 + rem;
    float run = 0.f;
    float a[8], xl[8];
    #pragma unroll
    for(int q=0;q<8;q++){ a[q] = apb[base + (size_t)q*2048]; xl[q] = xlb[base + (size_t)q*2048]; }
    for(int b=0; b<NC/8; b++){
        float a2[8], x2[8];
        if(b+1 < NC/8){
            #pragma unroll
            for(int q=0;q<8;q++){
                size_t off = base + (size_t)((b+1)*8+q)*2048;
                a2[q] = apb[off]; x2[q] = xlb[off];
            }
        }
        #pragma unroll
        for(int q=0;q<8;q++){
            size_t off = base + (size_t)(b*8+q)*2048;
            apb[off] = run;                 // becomes x_init
            run = a[q]*run + xl[q];
        }
        #pragma unroll
        for(int q=0;q<8;q++){ a[q] = a2[q]; xl[q] = x2[q]; }
    }
}

// ================= S2: rescan with x_init, emit y =================
__global__ __launch_bounds__(256) void k_S2(const float* __restrict__ xc_t,
                                            const float* __restrict__ bcd,
                                            const float* __restrict__ dtw,
                                            const float* __restrict__ dtb,
                                            const float* __restrict__ A_logs,
                                            const float* __restrict__ Dsv,   // (K*DI)
                                            const float* __restrict__ apb,   // x_init
                                            float* __restrict__ yk){         // (K,L,DI)
    int u = blockIdx.x;
    int k = u >> 8, cc = u & (NC-1);
    int l0 = cc*CH;
    int t = threadIdx.x;

    __shared__ float xt[CH*132];
    __shared__ float Bt[256];
    __shared__ float Ct[256];
    __shared__ float dtt[64];

    #pragma unroll
    for(int q=0;q<2;q++){
        int lin = q*256 + t;
        int row = lin >> 5, c4 = lin & 31;
        int p = perm_in(k, l0 + row);
        float4 v = ((const float4*)(xc_t + (size_t)p*DI))[c4];
        *((float4*)(xt + row*132 + c4*4)) = v;
    }
    {
        size_t b0 = (size_t)u*576;
        float v0 = bcd[b0 + t];
        float v1 = bcd[b0 + 256 + t];
        if(t < 64) dtt[t] = v0; else Bt[t-64] = v0;
        if(t < 64) Bt[192+t] = v1; else Ct[t-64] = v1;
        if(t < 64) Ct[192+t] = bcd[b0 + 512 + t];
    }
    __syncthreads();

    int d = t >> 1, nh = t & 1;
    float4 w4 = ((const float4*)dtw)[(size_t)k*DI + d];
    float  bb = dtb[k*DI + d];
    float  Dv = Dsv[k*DI + d];
    float A[8];
    {
        const float4* ar = (const float4*)(A_logs + ((size_t)k*DI + d)*NS + nh*8);
        #pragma unroll
        for(int q=0;q<2;q++){
            float4 a4 = ar[q];
            A[q*4+0] = -__expf(a4.x); A[q*4+1] = -__expf(a4.y);
            A[q*4+2] = -__expf(a4.z); A[q*4+3] = -__expf(a4.w);
        }
    }
    float xs[8];
    {
        const float4* ir = (const float4*)(apb + (size_t)u*2048 + d*16 + nh*8);
        #pragma unroll
        for(int q=0;q<2;q++){
            float4 v = ir[q];
            xs[q*4]=v.x; xs[q*4+1]=v.y; xs[q*4+2]=v.z; xs[q*4+3]=v.w;
        }
    }
    #pragma unroll
    for(int i=0;i<CH;i++){
        float dv = bb + w4.x*dtt[i] + w4.y*dtt[16+i] + w4.z*dtt[32+i] + w4.w*dtt[48+i];
        float delta = softplus_f(dv);
        float uu = xt[i*132 + d];
        float du = delta*uu;
        const float* Bi = Bt + i*16 + nh*8;
        const float* Ci = Ct + i*16 + nh*8;
        float y = 0.f;
        #pragma unroll
        for(int n=0;n<8;n++){
            float da = __expf(delta*A[n]);
            xs[n] = da*xs[n] + du*Bi[n];
            y += xs[n]*Ci[n];
        }
        y += __shfl_xor(y, 1, 64);           // partner = other n-half, same d
        if(nh == 0)
            yk[(size_t)u*2048 + i*128 + d] = y + uu*Dv;
    }
}

// ================= D: gather 6 dirs + LN + gate + out-proj =================
// 256 threads: ph = t>>7 selects pixel within concurrent pair; 2 sequential pairs
__global__ __launch_bounds__(256) void k_D(const float* __restrict__ yk,
                                           const float* __restrict__ sz,
                                           const float* __restrict__ ln_g,
                                           const float* __restrict__ ln_b,
                                           const float* __restrict__ W_out, // (CM,DI)
                                           float* __restrict__ out){        // (L,CM)
    __shared__ float ms[2][DI];
    __shared__ float po[2][DI];
    __shared__ float red[2][2][2];
    int t = threadIdx.x;
    int ph = t >> 7, d = t & 127;
    int o = d & 63, hf = d >> 6;
    float4 wo[16];
    const float4* wr4 = (const float4*)(W_out + (size_t)o*DI + hf*64);
    #pragma unroll
    for(int q=0;q<16;q++) wo[q] = wr4[q];
    float g = ln_g[d], bc = ln_b[d];

    int bp = blockIdx.x*4;
    #pragma unroll
    for(int it2=0; it2<2; it2++){
        int pg = bp + it2*2 + ph;
        int tp = ((pg&63)<<6) | (pg>>6);
        float y;
        y  = yk[((size_t)0*L + pg)*DI + d];
        y += yk[((size_t)1*L + tp)*DI + d];
        y += yk[((size_t)2*L + (L-1-pg))*DI + d];
        y += yk[((size_t)3*L + (L-1-tp))*DI + d];
        y += yk[((size_t)4*L + rankp(pg))*DI + d];
        y += yk[((size_t)5*L + rankp(L-1-pg))*DI + d];
        float s1 = y, s2 = y*y;
        #pragma unroll
        for(int m=1;m<64;m<<=1){ s1 += __shfl_xor(s1,m,64); s2 += __shfl_xor(s2,m,64); }
        __syncthreads();
        if((d&63)==0){ red[ph][hf][0] = s1; red[ph][hf][1] = s2; }
        __syncthreads();
        float mu  = (red[ph][0][0]+red[ph][1][0]) * (1.f/DI);
        float var = (red[ph][0][1]+red[ph][1][1]) * (1.f/DI) - mu*mu;
        float yh = (y-mu)*rsqrtf(var+1e-5f)*g + bc;
        ms[ph][d] = yh * sz[(size_t)pg*DI + d];
        __syncthreads();
        float acc = 0.f;
        const float4* mr = (const float4*)(&ms[ph][0] + hf*64);
        #pragma unroll
        for(int q=0;q<16;q++){
            float4 xv = mr[q];
            acc += wo[q].x*xv.x + wo[q].y*xv.y + wo[q].z*xv.z + wo[q].w*xv.w;
        }
        po[ph][hf*64 + o] = acc;
        __syncthreads();
        if(d < 64) out[(size_t)pg*CM + d] = po[ph][d] + po[ph][64+d];
    }
}

extern "C" void kernel_launch(void* const* d_in, const int* in_sizes, int n_in,
                              void* d_out, int out_size, void* d_ws, size_t ws_size,
                              hipStream_t stream) {
    const float* x      = (const float*)d_in[0];
    const float* W_in   = (const float*)d_in[1];
    const float* conv_w = (const float*)d_in[2];
    const float* conv_b = (const float*)d_in[3];
    const float* xpw    = (const float*)d_in[4];
    const float* dtw    = (const float*)d_in[5];
    const float* dtb    = (const float*)d_in[6];
    const float* A_logs = (const float*)d_in[7];
    const float* Dsv    = (const float*)d_in[8];
    const float* ln_g   = (const float*)d_in[9];
    const float* ln_b   = (const float*)d_in[10];
    const float* W_out  = (const float*)d_in[11];
    float* out = (float*)d_out;

    float* ws = (float*)d_ws;
    float* xc_t = ws;                           // L*DI
    float* sz   = xc_t + (size_t)L*DI;          // L*DI
    float* apb  = sz   + (size_t)L*DI;          // NU*2048
    float* xlb  = apb  + (size_t)NU*2048;       // NU*2048
    float* bcd  = xlb  + (size_t)NU*2048;       // NU*576
    float* yk   = bcd  + (size_t)NU*576;        // K*L*DI

    k_front<<<256, 256, 0, stream>>>(x, W_in, conv_w, conv_b, xc_t, sz);
    k_S1   <<<NU, 256, 0, stream>>>(xc_t, xpw, dtw, dtb, A_logs, apb, xlb, bcd);
    k_B    <<<96, 128, 0, stream>>>(apb, xlb);
    k_S2   <<<NU, 256, 0, stream>>>(xc_t, bcd, dtw, dtb, A_logs, Dsv, apb, yk);
    k_D    <<<L/4, 256, 0, stream>>>(yk, sz, ln_g, ln_b, W_out, out);
}